// Round 11
// baseline (431.741 us; speedup 1.0000x reference)
//
#include <hip/hip_runtime.h>

#define NN 20000
#define NE 640000
#define NR 8
#define NSEG (NN * NR)
#define KCAT 2304            // logical K: 256 self + 8*256 relations
#define KA   2048            // A stores only the 8 relation blocks
#define CH1 256
#define CH2 128

typedef __attribute__((ext_vector_type(8))) short short8;
typedef __attribute__((ext_vector_type(4))) float f32x4;

#define AS_GLOBAL __attribute__((address_space(1)))
#define AS_LDS    __attribute__((address_space(3)))

__device__ __forceinline__ float bf2f(unsigned short u) {
    unsigned int x = ((unsigned int)u) << 16;
    return __builtin_bit_cast(float, x);
}
__device__ __forceinline__ unsigned short f2bf(float f) {
    unsigned int u = __builtin_bit_cast(unsigned int, f);
    u = (u + 0x7FFFu + ((u >> 16) & 1u)) >> 16;   // RNE
    return (unsigned short)u;
}

// ================= fused prologue: edge count + x->bf16 =================
__global__ void prologue1(const int* __restrict__ dst, const int* __restrict__ et,
                          int* __restrict__ cnt,
                          const float* __restrict__ x, unsigned short* __restrict__ xbf) {
    int gid = blockIdx.x * 256 + threadIdx.x;
    if (gid < NN * 64) {
        float4 v = reinterpret_cast<const float4*>(x)[gid];
        ushort4 o;
        o.x = f2bf(v.x); o.y = f2bf(v.y); o.z = f2bf(v.z); o.w = f2bf(v.w);
        reinterpret_cast<ushort4*>(xbf)[gid] = o;
    }
    if (gid < NE) atomicAdd(&cnt[et[gid] * NN + dst[gid]], 1);
}

// ================= scans =================
__global__ void scan1(const int* __restrict__ cnt, int* __restrict__ off,
                      int* __restrict__ bsum) {
    __shared__ int s[256];
    int i = blockIdx.x * 256 + threadIdx.x;
    int v = (i < NSEG) ? cnt[i] : 0;
    s[threadIdx.x] = v;
    __syncthreads();
    for (int d = 1; d < 256; d <<= 1) {
        int t = (threadIdx.x >= d) ? s[threadIdx.x - d] : 0;
        __syncthreads();
        s[threadIdx.x] += t;
        __syncthreads();
    }
    if (i < NSEG) off[i] = s[threadIdx.x] - v;
    if (threadIdx.x == 255) bsum[blockIdx.x] = s[255];
}

__global__ __launch_bounds__(1024) void scan2(int* __restrict__ bsum, int nb) {
    __shared__ int s[1024];
    int t = threadIdx.x;
    int v = (t < nb) ? bsum[t] : 0;
    s[t] = v;
    __syncthreads();
    for (int d = 1; d < 1024; d <<= 1) {
        int tv = (t >= d) ? s[t - d] : 0;
        __syncthreads();
        s[t] += tv;
        __syncthreads();
    }
    if (t < nb) bsum[t] = s[t] - v;   // exclusive
}

__global__ void scan3(int* __restrict__ off, const int* __restrict__ bsum,
                      int* __restrict__ cursor) {
    int i = blockIdx.x * 256 + threadIdx.x;
    if (i < NSEG) {
        int o = off[i] + bsum[blockIdx.x];
        off[i] = o;
        cursor[i] = o;
    }
}

__global__ void bucket_kernel(const int* __restrict__ src, const int* __restrict__ dst,
                              const int* __restrict__ et, int* __restrict__ cursor,
                              int* __restrict__ ss) {
    int e = blockIdx.x * blockDim.x + threadIdx.x;
    if (e < NE) {
        int p = atomicAdd(&cursor[et[e] * NN + dst[e]], 1);
        ss[p] = src[e];
    }
}

// ================= both weight transposes in one kernel =================
__global__ void build_wt_all(const float* __restrict__ root1, const float* __restrict__ W1,
                             const float* __restrict__ root2, const float* __restrict__ W2,
                             unsigned short* __restrict__ W1T, unsigned short* __restrict__ W2T) {
    int i = blockIdx.x * 256 + threadIdx.x;
    if (i < CH1 * KCAT) {
        int n = i / KCAT, k = i - n * KCAT;
        float v = (k < 256) ? root1[(size_t)k * CH1 + n] : W1[(size_t)(k - 256) * CH1 + n];
        W1T[(size_t)n * KCAT + k] = f2bf(v);
    } else if (i < (CH1 + CH2) * KCAT) {
        int j = i - CH1 * KCAT;
        int n = j / KCAT, k = j - n * KCAT;
        float v = (k < 256) ? root2[(size_t)k * CH2 + n] : W2[(size_t)(k - 256) * CH2 + n];
        W2T[(size_t)n * KCAT + k] = f2bf(v);
    }
}

// ================= gather: one wave per (node, rel) segment =================
// Dual-row loads: lanes 0-31 cover row i (short8/lane), lanes 32-63 row i+1.
// 4 dual loads/batch = 8 rows in flight. Cross-half combine via shfl_xor(32).
__global__ __launch_bounds__(256) void gather_all(const unsigned short* __restrict__ xb,
                                                  const int* __restrict__ ss,
                                                  const int* __restrict__ off,
                                                  const int* __restrict__ cnt,
                                                  unsigned short* __restrict__ A,
                                                  int n0, int rows) {
    int wid  = blockIdx.x * 4 + (threadIdx.x >> 6);
    int lane = threadIdx.x & 63;
    if (wid >= rows * NR) return;
    int n = wid >> 3;          // NR == 8
    int r = wid & 7;
    int idx  = r * NN + (n0 + n);
    int base = off[idx];
    int c    = cnt[idx];
    int half = lane >> 5;      // 0: even rows, 1: odd rows
    int hl   = lane & 31;      // channel chunk: 8 shorts at hl*8

    const f32x4 z = {0.f, 0.f, 0.f, 0.f};
    f32x4 aL0 = z, aL1 = z, aL2 = z, aL3 = z;   // channels hl*8 .. hl*8+3
    f32x4 aH0 = z, aH1 = z, aH2 = z, aH3 = z;   // channels hl*8+4 .. hl*8+7

    int jj = 0;
    while (jj < c) {
        int m = c - jj; m = (m > 8) ? 8 : m;    // wave-uniform
        // hoist index loads (uniform addresses -> broadcast)
        int s0 = ss[base + jj + 0];
        int s1 = (m > 1) ? ss[base + jj + 1] : s0;
        int s2 = (m > 2) ? ss[base + jj + 2] : s0;
        int s3 = (m > 3) ? ss[base + jj + 3] : s0;
        int s4 = (m > 4) ? ss[base + jj + 4] : s0;
        int s5 = (m > 5) ? ss[base + jj + 5] : s0;
        int s6 = (m > 6) ? ss[base + jj + 6] : s0;
        int s7 = (m > 7) ? ss[base + jj + 7] : s0;
        // dual-row loads: batch b covers rows 2b (half0) and 2b+1 (half1)
        int r0 = half ? s1 : s0;  bool v0 = (0 + half) < m;
        int r1 = half ? s3 : s2;  bool v1 = (2 + half) < m;
        int r2 = half ? s5 : s4;  bool v2 = (4 + half) < m;
        int r3 = half ? s7 : s6;  bool v3 = (6 + half) < m;
        r0 = v0 ? r0 : s0; r1 = v1 ? r1 : s0;
        r2 = v2 ? r2 : s0; r3 = v3 ? r3 : s0;
        short8 w0 = *reinterpret_cast<const short8*>(xb + (size_t)r0 * 256 + hl * 8);
        short8 w1 = *reinterpret_cast<const short8*>(xb + (size_t)r1 * 256 + hl * 8);
        short8 w2 = *reinterpret_cast<const short8*>(xb + (size_t)r2 * 256 + hl * 8);
        short8 w3 = *reinterpret_cast<const short8*>(xb + (size_t)r3 * 256 + hl * 8);
        if (v0) {
            aL0.x += bf2f((unsigned short)w0[0]); aL0.y += bf2f((unsigned short)w0[1]);
            aL0.z += bf2f((unsigned short)w0[2]); aL0.w += bf2f((unsigned short)w0[3]);
            aH0.x += bf2f((unsigned short)w0[4]); aH0.y += bf2f((unsigned short)w0[5]);
            aH0.z += bf2f((unsigned short)w0[6]); aH0.w += bf2f((unsigned short)w0[7]);
        }
        if (v1) {
            aL1.x += bf2f((unsigned short)w1[0]); aL1.y += bf2f((unsigned short)w1[1]);
            aL1.z += bf2f((unsigned short)w1[2]); aL1.w += bf2f((unsigned short)w1[3]);
            aH1.x += bf2f((unsigned short)w1[4]); aH1.y += bf2f((unsigned short)w1[5]);
            aH1.z += bf2f((unsigned short)w1[6]); aH1.w += bf2f((unsigned short)w1[7]);
        }
        if (v2) {
            aL2.x += bf2f((unsigned short)w2[0]); aL2.y += bf2f((unsigned short)w2[1]);
            aL2.z += bf2f((unsigned short)w2[2]); aL2.w += bf2f((unsigned short)w2[3]);
            aH2.x += bf2f((unsigned short)w2[4]); aH2.y += bf2f((unsigned short)w2[5]);
            aH2.z += bf2f((unsigned short)w2[6]); aH2.w += bf2f((unsigned short)w2[7]);
        }
        if (v3) {
            aL3.x += bf2f((unsigned short)w3[0]); aL3.y += bf2f((unsigned short)w3[1]);
            aL3.z += bf2f((unsigned short)w3[2]); aL3.w += bf2f((unsigned short)w3[3]);
            aH3.x += bf2f((unsigned short)w3[4]); aH3.y += bf2f((unsigned short)w3[5]);
            aH3.z += bf2f((unsigned short)w3[6]); aH3.w += bf2f((unsigned short)w3[7]);
        }
        jj += m;
    }
    f32x4 sL = (aL0 + aL1) + (aL2 + aL3);
    f32x4 sH = (aH0 + aH1) + (aH2 + aH3);
    // cross-half combine (other half holds the other row-parity's partial sums)
    sL.x += __shfl_xor(sL.x, 32); sL.y += __shfl_xor(sL.y, 32);
    sL.z += __shfl_xor(sL.z, 32); sL.w += __shfl_xor(sL.w, 32);
    sH.x += __shfl_xor(sH.x, 32); sH.y += __shfl_xor(sH.y, 32);
    sH.z += __shfl_xor(sH.z, 32); sH.w += __shfl_xor(sH.w, 32);
    float inv = (c > 0) ? 1.f / (float)c : 0.f;
    short8 o;
    o[0] = (short)f2bf(sL.x * inv); o[1] = (short)f2bf(sL.y * inv);
    o[2] = (short)f2bf(sL.z * inv); o[3] = (short)f2bf(sL.w * inv);
    o[4] = (short)f2bf(sH.x * inv); o[5] = (short)f2bf(sH.y * inv);
    o[6] = (short)f2bf(sH.z * inv); o[7] = (short)f2bf(sH.w * inv);
    if (half == 0)
        *reinterpret_cast<short8*>(A + (size_t)n * KA + r * 256 + hl * 8) = o;
}

// ================= MFMA GEMM =================
// C[M x NOUT] = [Xsrc | A] @ BT^T + bias.  k<256 staged from Xsrc (L2-hot),
// k>=256 from A[M][KA].  BM=64 doubles block count vs 128 (CU overlap).
// Wave grid 2x2; wave tile (BM/2) x (BN/2).
template<int NOUT, int BM, int BN, bool RELU_BF16>
__global__ __launch_bounds__(256) void gemm_mfma(const unsigned short* __restrict__ A,
                                                 const unsigned short* __restrict__ Xsrc,
                                                 const unsigned short* __restrict__ BT,
                                                 const float* __restrict__ bias,
                                                 void* __restrict__ Cout,
                                                 int M, int mrow0) {
    constexpr int MI = BM / 32;     // 16-row frags per wave (BM/2/16)
    constexpr int NI = BN / 32;
    __shared__ __align__(16) unsigned short As[BM * 32];
    __shared__ __align__(16) unsigned short Bs[BN * 32];
    const int tid  = threadIdx.x;
    const int lane = tid & 63;
    const int w    = tid >> 6;
    const int wr   = w >> 1, wc = w & 1;
    const int wrow = wr * (MI * 16);
    const int wcol = wc * (NI * 16);
    const int row0 = blockIdx.x * BM;
    const int col0 = blockIdx.y * BN;

    const int srow = lane >> 2;
    const int skk  = (lane & 3) * 8;
    int ra0 = row0 + w * 16 + srow;
    int ra1 = row0 + 64 + w * 16 + srow;       // BM==128 only
    ra0 = (ra0 < M) ? ra0 : (M - 1);
    ra1 = (ra1 < M) ? ra1 : (M - 1);
    const unsigned short* pax0 = Xsrc + (size_t)(mrow0 + ra0) * 256 + skk;
    const unsigned short* pax1 = Xsrc + (size_t)(mrow0 + ra1) * 256 + skk;
    const unsigned short* paa0 = A + (size_t)ra0 * KA + skk - 256;   // +k0 valid for k0>=256
    const unsigned short* paa1 = A + (size_t)ra1 * KA + skk - 256;
    const unsigned short* pb0 = BT + (size_t)(col0 + w * 16 + srow) * KCAT + skk;
    const unsigned short* pb1 = BT + (size_t)(col0 + 64 + w * 16 + srow) * KCAT + skk; // BN==128 only
    unsigned short* lA0 = As + w * 512;
    unsigned short* lA1 = As + 2048 + w * 512;
    unsigned short* lB0 = Bs + w * 512;
    unsigned short* lB1 = Bs + 2048 + w * 512;

    f32x4 acc[MI][NI] = {};
    const int fr = lane & 15;
    const int ka = (lane >> 4) * 8;

    for (int k0 = 0; k0 < KCAT; k0 += 32) {
        const unsigned short* p0 = (k0 < 256) ? (pax0 + k0) : (paa0 + k0);
        __builtin_amdgcn_global_load_lds((const AS_GLOBAL unsigned int*)p0,
                                         (AS_LDS unsigned int*)lA0, 16, 0, 0);
        if (BM == 128) {
            const unsigned short* p1 = (k0 < 256) ? (pax1 + k0) : (paa1 + k0);
            __builtin_amdgcn_global_load_lds((const AS_GLOBAL unsigned int*)p1,
                                             (AS_LDS unsigned int*)lA1, 16, 0, 0);
        }
        __builtin_amdgcn_global_load_lds((const AS_GLOBAL unsigned int*)(pb0 + k0),
                                         (AS_LDS unsigned int*)lB0, 16, 0, 0);
        if (BN == 128)
            __builtin_amdgcn_global_load_lds((const AS_GLOBAL unsigned int*)(pb1 + k0),
                                             (AS_LDS unsigned int*)lB1, 16, 0, 0);
        __syncthreads();

        short8 af[MI], bfrag[NI];
        #pragma unroll
        for (int i = 0; i < MI; ++i)
            af[i] = *reinterpret_cast<const short8*>(&As[(wrow + i * 16 + fr) * 32 + ka]);
        #pragma unroll
        for (int i = 0; i < NI; ++i)
            bfrag[i] = *reinterpret_cast<const short8*>(&Bs[(wcol + i * 16 + fr) * 32 + ka]);
        #pragma unroll
        for (int mi = 0; mi < MI; ++mi)
            #pragma unroll
            for (int ni = 0; ni < NI; ++ni)
                acc[mi][ni] = __builtin_amdgcn_mfma_f32_16x16x32_bf16(af[mi], bfrag[ni], acc[mi][ni], 0, 0, 0);
        __syncthreads();
    }

    #pragma unroll
    for (int mi = 0; mi < MI; ++mi) {
        #pragma unroll
        for (int q = 0; q < 4; ++q) {
            int gm = row0 + wrow + mi * 16 + (lane >> 4) * 4 + q;
            if (gm >= M) continue;
            #pragma unroll
            for (int ni = 0; ni < NI; ++ni) {
                int gn = col0 + wcol + ni * 16 + fr;
                float v = acc[mi][ni][q] + bias[gn];
                if (RELU_BF16) {
                    v = fmaxf(v, 0.f);
                    ((unsigned short*)Cout)[(size_t)(mrow0 + gm) * NOUT + gn] = f2bf(v);
                } else {
                    ((float*)Cout)[(size_t)(mrow0 + gm) * NOUT + gn] = v;
                }
            }
        }
    }
}

// ================= launch =================
extern "C" void kernel_launch(void* const* d_in, const int* in_sizes, int n_in,
                              void* d_out, int out_size, void* d_ws, size_t ws_size,
                              hipStream_t stream) {
    const float* x     = (const float*)d_in[0];
    const float* W1    = (const float*)d_in[1];
    const float* root1 = (const float*)d_in[2];
    const float* b1    = (const float*)d_in[3];
    const float* W2    = (const float*)d_in[4];
    const float* root2 = (const float*)d_in[5];
    const float* b2    = (const float*)d_in[6];
    const int*   ei    = (const int*)d_in[7];
    const int*   et    = (const int*)d_in[8];
    const int* src = ei;
    const int* dst = ei + NE;
    float* out = (float*)d_out;

    char* ws = (char*)d_ws;
    int*            cnt    = (int*)(ws + 0);           // 640000
    int*            off    = (int*)(ws + 640000);      // 640000
    int*            cursor = (int*)(ws + 1280000);     // 640000
    int*            bsum   = (int*)(ws + 1920000);     // pad to 3072
    int*            ss     = (int*)(ws + 1923072);     // 2560000
    unsigned short* x_bf   = (unsigned short*)(ws + 4483072);   // 10,240,000
    unsigned short* h_bf   = (unsigned short*)(ws + 14723072);  // 10,240,000
    unsigned short* W1T    = (unsigned short*)(ws + 24963072);  // 1,179,648
    unsigned short* W2T    = (unsigned short*)(ws + 26142720);  // 589,824
    unsigned short* A      = (unsigned short*)(ws + 26732544);  // up to 81,920,000

    // chunk rows by available workspace for A ([rows][KA] bf16)
    size_t availA = (ws_size > 26732544) ? ws_size - 26732544 : 0;
    int rowsC = (int)(availA / ((size_t)KA * 2));
    if (rowsC > NN) rowsC = NN;
    if (rowsC >= 256) rowsC &= ~127;
    if (rowsC < 1) rowsC = 1;

    const int NB = (NSEG + 255) / 256;   // 625

    // CSR + conversions
    hipMemsetAsync(cnt, 0, (size_t)NSEG * 4, stream);
    prologue1<<<(NN * 64 + 255) / 256, 256, 0, stream>>>(dst, et, cnt, x, x_bf);
    scan1<<<NB, 256, 0, stream>>>(cnt, off, bsum);
    scan2<<<1, 1024, 0, stream>>>(bsum, NB);
    scan3<<<NB, 256, 0, stream>>>(off, bsum, cursor);
    bucket_kernel<<<(NE + 255) / 256, 256, 0, stream>>>(src, dst, et, cursor, ss);
    build_wt_all<<<((CH1 + CH2) * KCAT + 255) / 256, 256, 0, stream>>>(root1, W1, root2, W2, W1T, W2T);

    // layer 1: h_bf = relu([x_bf | Agg(x)] @ W1T^T + b1)   [bf16 out]
    for (int n0 = 0; n0 < NN; n0 += rowsC) {
        int rows = (NN - n0 < rowsC) ? (NN - n0) : rowsC;
        gather_all<<<(rows * NR + 3) / 4, 256, 0, stream>>>(x_bf, ss, off, cnt, A, n0, rows);
        dim3 g((rows + 63) / 64, CH1 / 128);
        gemm_mfma<CH1, 64, 128, true><<<g, 256, 0, stream>>>(A, x_bf, W1T, b1, h_bf, rows, n0);
    }
    // layer 2: out = [h_bf | Agg(h)] @ W2T^T + b2   [fp32 out]
    for (int n0 = 0; n0 < NN; n0 += rowsC) {
        int rows = (NN - n0 < rowsC) ? (NN - n0) : rowsC;
        gather_all<<<(rows * NR + 3) / 4, 256, 0, stream>>>(h_bf, ss, off, cnt, A, n0, rows);
        dim3 g((rows + 63) / 64, CH2 / 64);
        gemm_mfma<CH2, 64, 64, false><<<g, 256, 0, stream>>>(A, h_bf, W2T, b2, out, rows, n0);
    }
}

// Round 12
// 419.176 us; speedup vs baseline: 1.0300x; 1.0300x over previous
//
#include <hip/hip_runtime.h>

#define NN 20000
#define NE 640000
#define NR 8
#define NSEG (NN * NR)
#define KCAT 2304            // logical K: 256 self + 8*256 relations
#define KA   2048            // A stores only the 8 relation blocks
#define CH1 256
#define CH2 128

typedef __attribute__((ext_vector_type(8))) short short8;
typedef __attribute__((ext_vector_type(4))) float f32x4;

#define AS_GLOBAL __attribute__((address_space(1)))
#define AS_LDS    __attribute__((address_space(3)))

__device__ __forceinline__ float bf2f(unsigned short u) {
    unsigned int x = ((unsigned int)u) << 16;
    return __builtin_bit_cast(float, x);
}
__device__ __forceinline__ unsigned short f2bf(float f) {
    unsigned int u = __builtin_bit_cast(unsigned int, f);
    u = (u + 0x7FFFu + ((u >> 16) & 1u)) >> 16;   // RNE
    return (unsigned short)u;
}
__device__ __forceinline__ f32x4 cvt4(ushort4 v) {
    f32x4 r;
    r.x = bf2f(v.x); r.y = bf2f(v.y); r.z = bf2f(v.z); r.w = bf2f(v.w);
    return r;
}

// ================= fused prologue: edge count + x->bf16 =================
__global__ void prologue1(const int* __restrict__ dst, const int* __restrict__ et,
                          int* __restrict__ cnt,
                          const float* __restrict__ x, unsigned short* __restrict__ xbf) {
    int gid = blockIdx.x * 256 + threadIdx.x;
    if (gid < NN * 64) {
        float4 v = reinterpret_cast<const float4*>(x)[gid];
        ushort4 o;
        o.x = f2bf(v.x); o.y = f2bf(v.y); o.z = f2bf(v.z); o.w = f2bf(v.w);
        reinterpret_cast<ushort4*>(xbf)[gid] = o;
    }
    if (gid < NE) atomicAdd(&cnt[et[gid] * NN + dst[gid]], 1);
}

// ================= scans =================
__global__ void scan1(const int* __restrict__ cnt, int* __restrict__ off,
                      int* __restrict__ bsum) {
    __shared__ int s[256];
    int i = blockIdx.x * 256 + threadIdx.x;
    int v = (i < NSEG) ? cnt[i] : 0;
    s[threadIdx.x] = v;
    __syncthreads();
    for (int d = 1; d < 256; d <<= 1) {
        int t = (threadIdx.x >= d) ? s[threadIdx.x - d] : 0;
        __syncthreads();
        s[threadIdx.x] += t;
        __syncthreads();
    }
    if (i < NSEG) off[i] = s[threadIdx.x] - v;
    if (threadIdx.x == 255) bsum[blockIdx.x] = s[255];
}

__global__ __launch_bounds__(1024) void scan2(int* __restrict__ bsum, int nb) {
    __shared__ int s[1024];
    int t = threadIdx.x;
    int v = (t < nb) ? bsum[t] : 0;
    s[t] = v;
    __syncthreads();
    for (int d = 1; d < 1024; d <<= 1) {
        int tv = (t >= d) ? s[t - d] : 0;
        __syncthreads();
        s[t] += tv;
        __syncthreads();
    }
    if (t < nb) bsum[t] = s[t] - v;   // exclusive
}

__global__ void scan3(int* __restrict__ off, const int* __restrict__ bsum,
                      int* __restrict__ cursor) {
    int i = blockIdx.x * 256 + threadIdx.x;
    if (i < NSEG) {
        int o = off[i] + bsum[blockIdx.x];
        off[i] = o;
        cursor[i] = o;
    }
}

__global__ void bucket_kernel(const int* __restrict__ src, const int* __restrict__ dst,
                              const int* __restrict__ et, int* __restrict__ cursor,
                              int* __restrict__ ss) {
    int e = blockIdx.x * blockDim.x + threadIdx.x;
    if (e < NE) {
        int p = atomicAdd(&cursor[et[e] * NN + dst[e]], 1);
        ss[p] = src[e];
    }
}

// ================= both weight transposes in one kernel =================
__global__ void build_wt_all(const float* __restrict__ root1, const float* __restrict__ W1,
                             const float* __restrict__ root2, const float* __restrict__ W2,
                             unsigned short* __restrict__ W1T, unsigned short* __restrict__ W2T) {
    int i = blockIdx.x * 256 + threadIdx.x;
    if (i < CH1 * KCAT) {
        int n = i / KCAT, k = i - n * KCAT;
        float v = (k < 256) ? root1[(size_t)k * CH1 + n] : W1[(size_t)(k - 256) * CH1 + n];
        W1T[(size_t)n * KCAT + k] = f2bf(v);
    } else if (i < (CH1 + CH2) * KCAT) {
        int j = i - CH1 * KCAT;
        int n = j / KCAT, k = j - n * KCAT;
        float v = (k < 256) ? root2[(size_t)k * CH2 + n] : W2[(size_t)(k - 256) * CH2 + n];
        W2T[(size_t)n * KCAT + k] = f2bf(v);
    }
}

// ================= gather: one wave per (node, rel) segment =================
// Round-10 form (proven 58us): unroll-4, 4 independent row-gathers in flight.
__global__ __launch_bounds__(256) void gather_all(const unsigned short* __restrict__ xb,
                                                  const int* __restrict__ ss,
                                                  const int* __restrict__ off,
                                                  const int* __restrict__ cnt,
                                                  unsigned short* __restrict__ A,
                                                  int n0, int rows) {
    int wid  = blockIdx.x * 4 + (threadIdx.x >> 6);
    int lane = threadIdx.x & 63;
    if (wid >= rows * NR) return;
    int n = wid >> 3;          // NR == 8
    int r = wid & 7;
    int idx  = r * NN + (n0 + n);
    int base = off[idx];
    int c    = cnt[idx];

    f32x4 z = {0.f, 0.f, 0.f, 0.f};
    f32x4 a0 = z, a1 = z, a2 = z, a3 = z;
    int jj = 0;
    for (; jj + 4 <= c; jj += 4) {
        int s0 = ss[base + jj + 0];
        int s1 = ss[base + jj + 1];
        int s2 = ss[base + jj + 2];
        int s3 = ss[base + jj + 3];
        ushort4 v0 = reinterpret_cast<const ushort4*>(xb + (size_t)s0 * 256)[lane];
        ushort4 v1 = reinterpret_cast<const ushort4*>(xb + (size_t)s1 * 256)[lane];
        ushort4 v2 = reinterpret_cast<const ushort4*>(xb + (size_t)s2 * 256)[lane];
        ushort4 v3 = reinterpret_cast<const ushort4*>(xb + (size_t)s3 * 256)[lane];
        a0 += cvt4(v0); a1 += cvt4(v1); a2 += cvt4(v2); a3 += cvt4(v3);
    }
    int rem = c - jj;   // 0..3, wave-uniform
    if (rem > 0) {
        int s0 = ss[base + jj + 0];
        int s1 = (rem > 1) ? ss[base + jj + 1] : s0;
        int s2 = (rem > 2) ? ss[base + jj + 2] : s0;
        ushort4 v0 = reinterpret_cast<const ushort4*>(xb + (size_t)s0 * 256)[lane];
        ushort4 v1 = (rem > 1) ? reinterpret_cast<const ushort4*>(xb + (size_t)s1 * 256)[lane] : make_ushort4(0,0,0,0);
        ushort4 v2 = (rem > 2) ? reinterpret_cast<const ushort4*>(xb + (size_t)s2 * 256)[lane] : make_ushort4(0,0,0,0);
        a0 += cvt4(v0);
        if (rem > 1) a1 += cvt4(v1);
        if (rem > 2) a2 += cvt4(v2);
    }
    f32x4 acc = (a0 + a1) + (a2 + a3);
    float inv = (c > 0) ? 1.f / (float)c : 0.f;
    ushort4 o;
    o.x = f2bf(acc.x * inv); o.y = f2bf(acc.y * inv);
    o.z = f2bf(acc.z * inv); o.w = f2bf(acc.w * inv);
    reinterpret_cast<ushort4*>(A + (size_t)n * KA + r * 256)[lane] = o;
}

// ================= MFMA GEMM, K_STEP=64 =================
// C[M x NOUT] = [Xsrc | A] @ BT^T + bias.  k<256 staged from Xsrc (L2-hot),
// k>=256 from A[M][KA].  BM=64; 36 K-steps (halved barrier count vs K_STEP=32).
// LDS rows are 64 shorts; one gload_lds instr covers 8 rows (8 lanes/row x 16B).
template<int NOUT, int BN, bool RELU_BF16>
__global__ __launch_bounds__(256) void gemm_mfma(const unsigned short* __restrict__ A,
                                                 const unsigned short* __restrict__ Xsrc,
                                                 const unsigned short* __restrict__ BT,
                                                 const float* __restrict__ bias,
                                                 void* __restrict__ Cout,
                                                 int M, int mrow0) {
    constexpr int MI = 2;           // BM=64 -> wave tile 32 rows
    constexpr int NI = BN / 32;
    __shared__ __align__(16) unsigned short As[64 * 64];
    __shared__ __align__(16) unsigned short Bs[BN * 64];
    const int tid  = threadIdx.x;
    const int lane = tid & 63;
    const int w    = tid >> 6;
    const int wr   = w >> 1, wc = w & 1;
    const int wrow = wr * 32;
    const int wcol = wc * (NI * 16);
    const int row0 = blockIdx.x * 64;
    const int col0 = blockIdx.y * BN;

    const int srow8 = lane >> 3;        // 0..7
    const int skk8  = (lane & 7) * 8;   // 0..56 shorts
    // A-tile rows: wave w covers rows w*16 .. w*16+15 via 2 instrs (8 rows each)
    int ra0 = row0 + w * 16 + srow8;
    int ra1 = row0 + w * 16 + 8 + srow8;
    ra0 = (ra0 < M) ? ra0 : (M - 1);    // clamp OOB rows (garbage never stored)
    ra1 = (ra1 < M) ? ra1 : (M - 1);
    const unsigned short* pax0 = Xsrc + (size_t)(mrow0 + ra0) * 256 + skk8;
    const unsigned short* pax1 = Xsrc + (size_t)(mrow0 + ra1) * 256 + skk8;
    const unsigned short* paa0 = A + (size_t)ra0 * KA + skk8 - 256;   // +k0 valid for k0>=256
    const unsigned short* paa1 = A + (size_t)ra1 * KA + skk8 - 256;
    unsigned short* lA0 = As + (w * 16) * 64;
    unsigned short* lA1 = As + (w * 16 + 8) * 64;
    // B-tile rows: BN==128: wave w covers rows w*32..w*32+31 via 4 instrs;
    //              BN==64 : wave w covers rows w*16..w*16+15 via 2 instrs.
    constexpr int BI = BN / 32;         // instrs per wave for Bs (4 or 2)
    const unsigned short* pb[4];
    unsigned short* lB[4];
    #pragma unroll
    for (int i = 0; i < BI; ++i) {
        int rb = (BN == 128) ? (w * 32 + i * 8) : (w * 16 + i * 8);
        pb[i] = BT + (size_t)(col0 + rb + srow8) * KCAT + skk8;
        lB[i] = Bs + (rb) * 64;
    }

    f32x4 acc[MI][NI] = {};
    const int fr = lane & 15;
    const int ka = (lane >> 4) * 8;

    for (int k0 = 0; k0 < KCAT; k0 += 64) {
        const unsigned short* p0 = (k0 < 256) ? (pax0 + k0) : (paa0 + k0);
        const unsigned short* p1 = (k0 < 256) ? (pax1 + k0) : (paa1 + k0);
        __builtin_amdgcn_global_load_lds((const AS_GLOBAL unsigned int*)p0,
                                         (AS_LDS unsigned int*)lA0, 16, 0, 0);
        __builtin_amdgcn_global_load_lds((const AS_GLOBAL unsigned int*)p1,
                                         (AS_LDS unsigned int*)lA1, 16, 0, 0);
        #pragma unroll
        for (int i = 0; i < BI; ++i)
            __builtin_amdgcn_global_load_lds((const AS_GLOBAL unsigned int*)(pb[i] + k0),
                                             (AS_LDS unsigned int*)lB[i], 16, 0, 0);
        __syncthreads();

        short8 af[MI][2], bfr[NI][2];
        #pragma unroll
        for (int i = 0; i < MI; ++i) {
            af[i][0] = *reinterpret_cast<const short8*>(&As[(wrow + i * 16 + fr) * 64 + ka]);
            af[i][1] = *reinterpret_cast<const short8*>(&As[(wrow + i * 16 + fr) * 64 + 32 + ka]);
        }
        #pragma unroll
        for (int i = 0; i < NI; ++i) {
            bfr[i][0] = *reinterpret_cast<const short8*>(&Bs[(wcol + i * 16 + fr) * 64 + ka]);
            bfr[i][1] = *reinterpret_cast<const short8*>(&Bs[(wcol + i * 16 + fr) * 64 + 32 + ka]);
        }
        #pragma unroll
        for (int s = 0; s < 2; ++s)
            #pragma unroll
            for (int mi = 0; mi < MI; ++mi)
                #pragma unroll
                for (int ni = 0; ni < NI; ++ni)
                    acc[mi][ni] = __builtin_amdgcn_mfma_f32_16x16x32_bf16(af[mi][s], bfr[ni][s], acc[mi][ni], 0, 0, 0);
        __syncthreads();
    }

    #pragma unroll
    for (int mi = 0; mi < MI; ++mi) {
        #pragma unroll
        for (int q = 0; q < 4; ++q) {
            int gm = row0 + wrow + mi * 16 + (lane >> 4) * 4 + q;
            if (gm >= M) continue;
            #pragma unroll
            for (int ni = 0; ni < NI; ++ni) {
                int gn = col0 + wcol + ni * 16 + fr;
                float v = acc[mi][ni][q] + bias[gn];
                if (RELU_BF16) {
                    v = fmaxf(v, 0.f);
                    ((unsigned short*)Cout)[(size_t)(mrow0 + gm) * NOUT + gn] = f2bf(v);
                } else {
                    ((float*)Cout)[(size_t)(mrow0 + gm) * NOUT + gn] = v;
                }
            }
        }
    }
}

// ================= launch =================
extern "C" void kernel_launch(void* const* d_in, const int* in_sizes, int n_in,
                              void* d_out, int out_size, void* d_ws, size_t ws_size,
                              hipStream_t stream) {
    const float* x     = (const float*)d_in[0];
    const float* W1    = (const float*)d_in[1];
    const float* root1 = (const float*)d_in[2];
    const float* b1    = (const float*)d_in[3];
    const float* W2    = (const float*)d_in[4];
    const float* root2 = (const float*)d_in[5];
    const float* b2    = (const float*)d_in[6];
    const int*   ei    = (const int*)d_in[7];
    const int*   et    = (const int*)d_in[8];
    const int* src = ei;
    const int* dst = ei + NE;
    float* out = (float*)d_out;

    char* ws = (char*)d_ws;
    int*            cnt    = (int*)(ws + 0);           // 640000
    int*            off    = (int*)(ws + 640000);      // 640000
    int*            cursor = (int*)(ws + 1280000);     // 640000
    int*            bsum   = (int*)(ws + 1920000);     // pad to 3072
    int*            ss     = (int*)(ws + 1923072);     // 2560000
    unsigned short* x_bf   = (unsigned short*)(ws + 4483072);   // 10,240,000
    unsigned short* h_bf   = (unsigned short*)(ws + 14723072);  // 10,240,000
    unsigned short* W1T    = (unsigned short*)(ws + 24963072);  // 1,179,648
    unsigned short* W2T    = (unsigned short*)(ws + 26142720);  // 589,824
    unsigned short* A      = (unsigned short*)(ws + 26732544);  // up to 81,920,000

    // chunk rows by available workspace for A ([rows][KA] bf16)
    size_t availA = (ws_size > 26732544) ? ws_size - 26732544 : 0;
    int rowsC = (int)(availA / ((size_t)KA * 2));
    if (rowsC > NN) rowsC = NN;
    if (rowsC >= 256) rowsC &= ~127;
    if (rowsC < 1) rowsC = 1;

    const int NB = (NSEG + 255) / 256;   // 625

    // CSR + conversions
    hipMemsetAsync(cnt, 0, (size_t)NSEG * 4, stream);
    prologue1<<<(NN * 64 + 255) / 256, 256, 0, stream>>>(dst, et, cnt, x, x_bf);
    scan1<<<NB, 256, 0, stream>>>(cnt, off, bsum);
    scan2<<<1, 1024, 0, stream>>>(bsum, NB);
    scan3<<<NB, 256, 0, stream>>>(off, bsum, cursor);
    bucket_kernel<<<(NE + 255) / 256, 256, 0, stream>>>(src, dst, et, cursor, ss);
    build_wt_all<<<((CH1 + CH2) * KCAT + 255) / 256, 256, 0, stream>>>(root1, W1, root2, W2, W1T, W2T);

    // layer 1: h_bf = relu([x_bf | Agg(x)] @ W1T^T + b1)   [bf16 out]
    for (int n0 = 0; n0 < NN; n0 += rowsC) {
        int rows = (NN - n0 < rowsC) ? (NN - n0) : rowsC;
        gather_all<<<(rows * NR + 3) / 4, 256, 0, stream>>>(x_bf, ss, off, cnt, A, n0, rows);
        dim3 g((rows + 63) / 64, CH1 / 128);
        gemm_mfma<CH1, 128, true><<<g, 256, 0, stream>>>(A, x_bf, W1T, b1, h_bf, rows, n0);
    }
    // layer 2: out = [h_bf | Agg(h)] @ W2T^T + b2   [fp32 out]
    for (int n0 = 0; n0 < NN; n0 += rowsC) {
        int rows = (NN - n0 < rowsC) ? (NN - n0) : rowsC;
        gather_all<<<(rows * NR + 3) / 4, 256, 0, stream>>>(h_bf, ss, off, cnt, A, n0, rows);
        dim3 g((rows + 63) / 64, CH2 / 64);
        gemm_mfma<CH2, 64, false><<<g, 256, 0, stream>>>(A, h_bf, W2T, b2, out, rows, n0);
    }
}

// Round 13
// 380.605 us; speedup vs baseline: 1.1344x; 1.1013x over previous
//
#include <hip/hip_runtime.h>

#define NN 20000
#define NE 640000
#define NR 8
#define NSEG (NN * NR)
#define KCAT 2304            // logical K: 256 self + 8*256 relations
#define KA   2048            // A stores only the 8 relation blocks
#define CH1 256
#define CH2 128

typedef __attribute__((ext_vector_type(8))) short short8;
typedef __attribute__((ext_vector_type(4))) float f32x4;

#define AS_GLOBAL __attribute__((address_space(1)))
#define AS_LDS    __attribute__((address_space(3)))

__device__ __forceinline__ float bf2f(unsigned short u) {
    unsigned int x = ((unsigned int)u) << 16;
    return __builtin_bit_cast(float, x);
}
__device__ __forceinline__ unsigned short f2bf(float f) {
    unsigned int u = __builtin_bit_cast(unsigned int, f);
    u = (u + 0x7FFFu + ((u >> 16) & 1u)) >> 16;   // RNE
    return (unsigned short)u;
}
__device__ __forceinline__ f32x4 cvt4(ushort4 v) {
    f32x4 r;
    r.x = bf2f(v.x); r.y = bf2f(v.y); r.z = bf2f(v.z); r.w = bf2f(v.w);
    return r;
}

// ================= fused prologue: edge count + x->bf16 =================
__global__ void prologue1(const int* __restrict__ dst, const int* __restrict__ et,
                          int* __restrict__ cnt,
                          const float* __restrict__ x, unsigned short* __restrict__ xbf) {
    int gid = blockIdx.x * 256 + threadIdx.x;
    if (gid < NN * 64) {
        float4 v = reinterpret_cast<const float4*>(x)[gid];
        ushort4 o;
        o.x = f2bf(v.x); o.y = f2bf(v.y); o.z = f2bf(v.z); o.w = f2bf(v.w);
        reinterpret_cast<ushort4*>(xbf)[gid] = o;
    }
    if (gid < NE) atomicAdd(&cnt[et[gid] * NN + dst[gid]], 1);
}

// ================= scans =================
__global__ void scan1(const int* __restrict__ cnt, int* __restrict__ off,
                      int* __restrict__ bsum) {
    __shared__ int s[256];
    int i = blockIdx.x * 256 + threadIdx.x;
    int v = (i < NSEG) ? cnt[i] : 0;
    s[threadIdx.x] = v;
    __syncthreads();
    for (int d = 1; d < 256; d <<= 1) {
        int t = (threadIdx.x >= d) ? s[threadIdx.x - d] : 0;
        __syncthreads();
        s[threadIdx.x] += t;
        __syncthreads();
    }
    if (i < NSEG) off[i] = s[threadIdx.x] - v;
    if (threadIdx.x == 255) bsum[blockIdx.x] = s[255];
}

__global__ __launch_bounds__(1024) void scan2(int* __restrict__ bsum, int nb) {
    __shared__ int s[1024];
    int t = threadIdx.x;
    int v = (t < nb) ? bsum[t] : 0;
    s[t] = v;
    __syncthreads();
    for (int d = 1; d < 1024; d <<= 1) {
        int tv = (t >= d) ? s[t - d] : 0;
        __syncthreads();
        s[t] += tv;
        __syncthreads();
    }
    if (t < nb) bsum[t] = s[t] - v;   // exclusive
}

__global__ void scan3(int* __restrict__ off, const int* __restrict__ bsum,
                      int* __restrict__ cursor) {
    int i = blockIdx.x * 256 + threadIdx.x;
    if (i < NSEG) {
        int o = off[i] + bsum[blockIdx.x];
        off[i] = o;
        cursor[i] = o;
    }
}

__global__ void bucket_kernel(const int* __restrict__ src, const int* __restrict__ dst,
                              const int* __restrict__ et, int* __restrict__ cursor,
                              int* __restrict__ ss) {
    int e = blockIdx.x * blockDim.x + threadIdx.x;
    if (e < NE) {
        int p = atomicAdd(&cursor[et[e] * NN + dst[e]], 1);
        ss[p] = src[e];
    }
}

// ================= both weight transposes in one kernel =================
__global__ void build_wt_all(const float* __restrict__ root1, const float* __restrict__ W1,
                             const float* __restrict__ root2, const float* __restrict__ W2,
                             unsigned short* __restrict__ W1T, unsigned short* __restrict__ W2T) {
    int i = blockIdx.x * 256 + threadIdx.x;
    if (i < CH1 * KCAT) {
        int n = i / KCAT, k = i - n * KCAT;
        float v = (k < 256) ? root1[(size_t)k * CH1 + n] : W1[(size_t)(k - 256) * CH1 + n];
        W1T[(size_t)n * KCAT + k] = f2bf(v);
    } else if (i < (CH1 + CH2) * KCAT) {
        int j = i - CH1 * KCAT;
        int n = j / KCAT, k = j - n * KCAT;
        float v = (k < 256) ? root2[(size_t)k * CH2 + n] : W2[(size_t)(k - 256) * CH2 + n];
        W2T[(size_t)n * KCAT + k] = f2bf(v);
    }
}

// ================= gather: one wave per (node, rel) segment =================
// Round-10 form (proven 58us): unroll-4, 4 independent row-gathers in flight.
__global__ __launch_bounds__(256) void gather_all(const unsigned short* __restrict__ xb,
                                                  const int* __restrict__ ss,
                                                  const int* __restrict__ off,
                                                  const int* __restrict__ cnt,
                                                  unsigned short* __restrict__ A,
                                                  int n0, int rows) {
    int wid  = blockIdx.x * 4 + (threadIdx.x >> 6);
    int lane = threadIdx.x & 63;
    if (wid >= rows * NR) return;
    int n = wid >> 3;          // NR == 8
    int r = wid & 7;
    int idx  = r * NN + (n0 + n);
    int base = off[idx];
    int c    = cnt[idx];

    f32x4 z = {0.f, 0.f, 0.f, 0.f};
    f32x4 a0 = z, a1 = z, a2 = z, a3 = z;
    int jj = 0;
    for (; jj + 4 <= c; jj += 4) {
        int s0 = ss[base + jj + 0];
        int s1 = ss[base + jj + 1];
        int s2 = ss[base + jj + 2];
        int s3 = ss[base + jj + 3];
        ushort4 v0 = reinterpret_cast<const ushort4*>(xb + (size_t)s0 * 256)[lane];
        ushort4 v1 = reinterpret_cast<const ushort4*>(xb + (size_t)s1 * 256)[lane];
        ushort4 v2 = reinterpret_cast<const ushort4*>(xb + (size_t)s2 * 256)[lane];
        ushort4 v3 = reinterpret_cast<const ushort4*>(xb + (size_t)s3 * 256)[lane];
        a0 += cvt4(v0); a1 += cvt4(v1); a2 += cvt4(v2); a3 += cvt4(v3);
    }
    int rem = c - jj;   // 0..3, wave-uniform
    if (rem > 0) {
        int s0 = ss[base + jj + 0];
        int s1 = (rem > 1) ? ss[base + jj + 1] : s0;
        int s2 = (rem > 2) ? ss[base + jj + 2] : s0;
        ushort4 v0 = reinterpret_cast<const ushort4*>(xb + (size_t)s0 * 256)[lane];
        ushort4 v1 = (rem > 1) ? reinterpret_cast<const ushort4*>(xb + (size_t)s1 * 256)[lane] : make_ushort4(0,0,0,0);
        ushort4 v2 = (rem > 2) ? reinterpret_cast<const ushort4*>(xb + (size_t)s2 * 256)[lane] : make_ushort4(0,0,0,0);
        a0 += cvt4(v0);
        if (rem > 1) a1 += cvt4(v1);
        if (rem > 2) a2 += cvt4(v2);
    }
    f32x4 acc = (a0 + a1) + (a2 + a3);
    float inv = (c > 0) ? 1.f / (float)c : 0.f;
    ushort4 o;
    o.x = f2bf(acc.x * inv); o.y = f2bf(acc.y * inv);
    o.z = f2bf(acc.z * inv); o.w = f2bf(acc.w * inv);
    reinterpret_cast<ushort4*>(A + (size_t)n * KA + r * 256)[lane] = o;
}

// ================= MFMA GEMM, K_STEP=64, dbuf + counted vmcnt + XOR swizzle ====
// C[M x NOUT] = [Xsrc | A] @ BT^T + bias.
// LDS dest is linear (gload_lds HW constraint); global SOURCE chunk is
// pre-swizzled (chunk ^= row&7 within each 128B block); ds_read applies the
// same XOR -> 2-way banks (free).  STAGE(t+1) issued before compute(t);
// s_waitcnt vmcnt(N) + raw s_barrier keeps next tile's loads in flight.
template<int NOUT, int BN, bool RELU_BF16>
__global__ __launch_bounds__(256) void gemm_mfma(const unsigned short* __restrict__ A,
                                                 const unsigned short* __restrict__ Xsrc,
                                                 const unsigned short* __restrict__ BT,
                                                 const float* __restrict__ bias,
                                                 void* __restrict__ Cout,
                                                 int M, int mrow0) {
    constexpr int MI = 2;           // BM=64 -> wave tile 32 rows
    constexpr int NI = BN / 32;
    constexpr int BI = BN / 32;     // B-stage instrs per wave
    constexpr int NT = KCAT / 64;   // 36 K-steps
    __shared__ __align__(16) unsigned short As[2][64 * 64];
    __shared__ __align__(16) unsigned short Bs[2][BN * 64];
    const int tid  = threadIdx.x;
    const int lane = tid & 63;
    const int w    = tid >> 6;
    const int wr   = w >> 1, wc = w & 1;
    const int wrow = wr * 32;
    const int wcol = wc * (NI * 16);
    const int row0 = blockIdx.x * 64;
    const int col0 = blockIdx.y * BN;

    const int srow8 = lane >> 3;                    // row within 8-row group
    const int csw   = ((lane & 7) ^ srow8) * 8;     // swizzled source chunk (shorts)
    int ra0 = row0 + w * 16 + srow8;
    int ra1 = row0 + w * 16 + 8 + srow8;
    ra0 = (ra0 < M) ? ra0 : (M - 1);    // clamp OOB rows (garbage never stored)
    ra1 = (ra1 < M) ? ra1 : (M - 1);
    const unsigned short* pax0 = Xsrc + (size_t)(mrow0 + ra0) * 256 + csw;
    const unsigned short* pax1 = Xsrc + (size_t)(mrow0 + ra1) * 256 + csw;
    const unsigned short* paa0 = A + (size_t)ra0 * KA + csw - 256;   // +k0 valid for k0>=256
    const unsigned short* paa1 = A + (size_t)ra1 * KA + csw - 256;
    const unsigned short* pb[4];
    int rbofs[4];
    #pragma unroll
    for (int i = 0; i < BI; ++i) {
        int rb = (BN == 128) ? (w * 32 + i * 8) : (w * 16 + i * 8);
        rbofs[i] = rb * 64;
        pb[i] = BT + (size_t)(col0 + rb + srow8) * KCAT + csw;
    }
    const int lofsA0 = (w * 16) * 64;
    const int lofsA1 = (w * 16 + 8) * 64;

    f32x4 acc[MI][NI] = {};
    const int fr  = lane & 15;
    const int q   = lane >> 4;
    const int frx = fr & 7;

    auto STAGE = [&](int buf, int k0) {
        const unsigned short* p0 = (k0 < 256) ? (pax0 + k0) : (paa0 + k0);
        const unsigned short* p1 = (k0 < 256) ? (pax1 + k0) : (paa1 + k0);
        __builtin_amdgcn_global_load_lds((const AS_GLOBAL unsigned int*)p0,
                                         (AS_LDS unsigned int*)(&As[buf][lofsA0]), 16, 0, 0);
        __builtin_amdgcn_global_load_lds((const AS_GLOBAL unsigned int*)p1,
                                         (AS_LDS unsigned int*)(&As[buf][lofsA1]), 16, 0, 0);
        #pragma unroll
        for (int i = 0; i < BI; ++i)
            __builtin_amdgcn_global_load_lds((const AS_GLOBAL unsigned int*)(pb[i] + k0),
                                             (AS_LDS unsigned int*)(&Bs[buf][rbofs[i]]), 16, 0, 0);
    };

    STAGE(0, 0);
    for (int t = 0; t < NT; ++t) {
        if (t + 1 < NT) {
            STAGE((t + 1) & 1, (t + 1) * 64);
            if constexpr (BI == 4) asm volatile("s_waitcnt vmcnt(6)" ::: "memory");
            else                   asm volatile("s_waitcnt vmcnt(4)" ::: "memory");
        } else {
            asm volatile("s_waitcnt vmcnt(0)" ::: "memory");
        }
        __builtin_amdgcn_s_barrier();

        const unsigned short* Ab = &As[t & 1][0];
        const unsigned short* Bb = &Bs[t & 1][0];
        short8 af[MI][2], bfr[NI][2];
        #pragma unroll
        for (int i = 0; i < MI; ++i) {
            int rr = (wrow + i * 16 + fr) * 64;
            af[i][0] = *reinterpret_cast<const short8*>(&Ab[rr + ((q ^ frx) * 8)]);
            af[i][1] = *reinterpret_cast<const short8*>(&Ab[rr + (((4 + q) ^ frx) * 8)]);
        }
        #pragma unroll
        for (int i = 0; i < NI; ++i) {
            int rr = (wcol + i * 16 + fr) * 64;
            bfr[i][0] = *reinterpret_cast<const short8*>(&Bb[rr + ((q ^ frx) * 8)]);
            bfr[i][1] = *reinterpret_cast<const short8*>(&Bb[rr + (((4 + q) ^ frx) * 8)]);
        }
        #pragma unroll
        for (int s = 0; s < 2; ++s)
            #pragma unroll
            for (int mi = 0; mi < MI; ++mi)
                #pragma unroll
                for (int ni = 0; ni < NI; ++ni)
                    acc[mi][ni] = __builtin_amdgcn_mfma_f32_16x16x32_bf16(af[mi][s], bfr[ni][s], acc[mi][ni], 0, 0, 0);
        __builtin_amdgcn_s_barrier();
    }

    #pragma unroll
    for (int mi = 0; mi < MI; ++mi) {
        #pragma unroll
        for (int qq = 0; qq < 4; ++qq) {
            int gm = row0 + wrow + mi * 16 + (lane >> 4) * 4 + qq;
            if (gm >= M) continue;
            #pragma unroll
            for (int ni = 0; ni < NI; ++ni) {
                int gn = col0 + wcol + ni * 16 + fr;
                float v = acc[mi][ni][qq] + bias[gn];
                if (RELU_BF16) {
                    v = fmaxf(v, 0.f);
                    ((unsigned short*)Cout)[(size_t)(mrow0 + gm) * NOUT + gn] = f2bf(v);
                } else {
                    ((float*)Cout)[(size_t)(mrow0 + gm) * NOUT + gn] = v;
                }
            }
        }
    }
}

// ================= launch =================
extern "C" void kernel_launch(void* const* d_in, const int* in_sizes, int n_in,
                              void* d_out, int out_size, void* d_ws, size_t ws_size,
                              hipStream_t stream) {
    const float* x     = (const float*)d_in[0];
    const float* W1    = (const float*)d_in[1];
    const float* root1 = (const float*)d_in[2];
    const float* b1    = (const float*)d_in[3];
    const float* W2    = (const float*)d_in[4];
    const float* root2 = (const float*)d_in[5];
    const float* b2    = (const float*)d_in[6];
    const int*   ei    = (const int*)d_in[7];
    const int*   et    = (const int*)d_in[8];
    const int* src = ei;
    const int* dst = ei + NE;
    float* out = (float*)d_out;

    char* ws = (char*)d_ws;
    int*            cnt    = (int*)(ws + 0);           // 640000
    int*            off    = (int*)(ws + 640000);      // 640000
    int*            cursor = (int*)(ws + 1280000);     // 640000
    int*            bsum   = (int*)(ws + 1920000);     // pad to 3072
    int*            ss     = (int*)(ws + 1923072);     // 2560000
    unsigned short* x_bf   = (unsigned short*)(ws + 4483072);   // 10,240,000
    unsigned short* h_bf   = (unsigned short*)(ws + 14723072);  // 10,240,000
    unsigned short* W1T    = (unsigned short*)(ws + 24963072);  // 1,179,648
    unsigned short* W2T    = (unsigned short*)(ws + 26142720);  // 589,824
    unsigned short* A      = (unsigned short*)(ws + 26732544);  // up to 81,920,000

    // chunk rows by available workspace for A ([rows][KA] bf16)
    size_t availA = (ws_size > 26732544) ? ws_size - 26732544 : 0;
    int rowsC = (int)(availA / ((size_t)KA * 2));
    if (rowsC > NN) rowsC = NN;
    if (rowsC >= 256) rowsC &= ~127;
    if (rowsC < 1) rowsC = 1;

    const int NB = (NSEG + 255) / 256;   // 625

    // CSR + conversions
    hipMemsetAsync(cnt, 0, (size_t)NSEG * 4, stream);
    prologue1<<<(NN * 64 + 255) / 256, 256, 0, stream>>>(dst, et, cnt, x, x_bf);
    scan1<<<NB, 256, 0, stream>>>(cnt, off, bsum);
    scan2<<<1, 1024, 0, stream>>>(bsum, NB);
    scan3<<<NB, 256, 0, stream>>>(off, bsum, cursor);
    bucket_kernel<<<(NE + 255) / 256, 256, 0, stream>>>(src, dst, et, cursor, ss);
    build_wt_all<<<((CH1 + CH2) * KCAT + 255) / 256, 256, 0, stream>>>(root1, W1, root2, W2, W1T, W2T);

    // layer 1: h_bf = relu([x_bf | Agg(x)] @ W1T^T + b1)   [bf16 out]
    for (int n0 = 0; n0 < NN; n0 += rowsC) {
        int rows = (NN - n0 < rowsC) ? (NN - n0) : rowsC;
        gather_all<<<(rows * NR + 3) / 4, 256, 0, stream>>>(x_bf, ss, off, cnt, A, n0, rows);
        dim3 g((rows + 63) / 64, CH1 / 128);
        gemm_mfma<CH1, 128, true><<<g, 256, 0, stream>>>(A, x_bf, W1T, b1, h_bf, rows, n0);
    }
    // layer 2: out = [h_bf | Agg(h)] @ W2T^T + b2   [fp32 out]
    for (int n0 = 0; n0 < NN; n0 += rowsC) {
        int rows = (NN - n0 < rowsC) ? (NN - n0) : rowsC;
        gather_all<<<(rows * NR + 3) / 4, 256, 0, stream>>>(h_bf, ss, off, cnt, A, n0, rows);
        dim3 g((rows + 63) / 64, CH2 / 64);
        gemm_mfma<CH2, 64, false><<<g, 256, 0, stream>>>(A, h_bf, W2T, b2, out, rows, n0);
    }
}